// Round 18
// baseline (523.929 us; speedup 1.0000x reference)
//
#include <hip/hip_runtime.h>
#include <hip/hip_bf16.h>
#include <type_traits>
#include <utility>

typedef unsigned short u16;
typedef unsigned int u32;
typedef __attribute__((ext_vector_type(8))) short  s16x8;
typedef __attribute__((ext_vector_type(4))) short  s16x4;
typedef __attribute__((ext_vector_type(4))) float  f32x4;
typedef __attribute__((ext_vector_type(16))) float f32x16;
typedef __bf16 bf16x8_t __attribute__((ext_vector_type(8)));
typedef __bf16 bf16x2_t __attribute__((ext_vector_type(2)));

#define SEQ 2048
#define DMODEL 2048
#define NBATCH 4
#define DH 128
#define NB (NBATCH * SEQ)

// Q pre-scale: (1/sqrt(128)) * log2(e)  -> scores come out in log2 domain
#define QK_SCALE_LOG2 0.12754375f
// bias constants (log2 domain): valid = -24*log2e ; masked/pad = huge negative
#define BIAS_VALID  (-34.624681f)
#define BIAS_MASKED (-180.0f)

#if __has_builtin(__builtin_amdgcn_exp2f)
#define EXP2(x) __builtin_amdgcn_exp2f(x)
#else
#define EXP2(x) exp2f(x)
#endif

#define BARRIER __builtin_amdgcn_s_barrier()
#define LGKM0  asm volatile("s_waitcnt lgkmcnt(0)" ::: "memory")
#define VMCNT4 asm volatile("s_waitcnt vmcnt(4)" ::: "memory")
#define VMCNT0 asm volatile("s_waitcnt vmcnt(0)" ::: "memory")

static __device__ __forceinline__ u16 f2bf(float f) {
  unsigned u = __float_as_uint(f);
  u += 0x7fffu + ((u >> 16) & 1u);
  return (u16)(u >> 16);
}
static __device__ __forceinline__ float bf2f(u16 h) {
  return __uint_as_float(((unsigned)h) << 16);
}
static __device__ __forceinline__ u32 pack_bf16(float a, float b) {
  bf16x2_t t; t[0] = (__bf16)a; t[1] = (__bf16)b;
  return __builtin_bit_cast(u32, t);
}
// v_permlane32_swap_b32: after the op, a = {a.row0, b.row0}, b = {a.row1, b.row1}
static __device__ __forceinline__ void plswap(u32& a, u32& b) {
  asm("v_permlane32_swap_b32 %0, %1" : "+v"(a), "+v"(b));
}

// ---- MFMA wrappers: robust to short8 vs bf16x8 builtin signature ----
template <typename T, typename = void>
struct mfma_takes : std::false_type {};
template <typename T>
struct mfma_takes<T, std::void_t<decltype(__builtin_amdgcn_mfma_f32_16x16x32_bf16(
    std::declval<T>(), std::declval<T>(), std::declval<f32x4>(), 0, 0, 0))>>
    : std::true_type {};
using mfma_frag_t = std::conditional_t<mfma_takes<s16x8>::value, s16x8, bf16x8_t>;

static __device__ __forceinline__ f32x16 mfma32(s16x8 a, s16x8 b, f32x16 c) {
  return __builtin_amdgcn_mfma_f32_32x32x16_bf16(
      __builtin_bit_cast(mfma_frag_t, a), __builtin_bit_cast(mfma_frag_t, b), c, 0, 0, 0);
}

typedef const void __attribute__((address_space(1)))* gas_ptr;
typedef void __attribute__((address_space(3)))* las_ptr;
static __device__ __forceinline__ void gload16(const void* g, void* l) {
  __builtin_amdgcn_global_load_lds((gas_ptr)g, (las_ptr)l, 16, 0, 0);
}

static __device__ __forceinline__ s16x8 frag_from_words(u32 w0, u32 w1, u32 w2, u32 w3) {
  union { u32 w[4]; s16x8 v; } u;
  u.w[0] = w0; u.w[1] = w1; u.w[2] = w2; u.w[3] = w3;
  return u.v;
}

// ---------------- f32 -> bf16 convert helpers ----------------
static __device__ __forceinline__ void cvt8(const float* src, u16* dst, int i) {
  const float4* p = (const float4*)src + (size_t)i * 2;
  float4 a = p[0], b4 = p[1];
  s16x8 o;
  o[0] = (short)f2bf(a.x);  o[1] = (short)f2bf(a.y);
  o[2] = (short)f2bf(a.z);  o[3] = (short)f2bf(a.w);
  o[4] = (short)f2bf(b4.x); o[5] = (short)f2bf(b4.y);
  o[6] = (short)f2bf(b4.z); o[7] = (short)f2bf(b4.w);
  *(s16x8*)(dst + (size_t)i * 8) = o;
}

// query + 4 weights in one launch
__global__ void cvtall_k(const float* __restrict__ q, const float* __restrict__ a,
                         const float* __restrict__ b, const float* __restrict__ c,
                         const float* __restrict__ d, u16* __restrict__ oq,
                         u16* __restrict__ oa, u16* __restrict__ ob,
                         u16* __restrict__ oc, u16* __restrict__ od) {
  const int nq = 1 << 21, nw = 1 << 19;
  const int total = nq + 4 * nw;
  const int stride = (int)(gridDim.x * blockDim.x);
  for (int i = (int)(blockIdx.x * blockDim.x + threadIdx.x); i < total; i += stride) {
    if (i < nq) {
      cvt8(q, oq, i);
    } else {
      const int j = i - nq;
      const int seg = j >> 19, off = j & (nw - 1);
      const float* src = seg == 0 ? a : (seg == 1 ? b : (seg == 2 ? c : d));
      u16* dst = seg == 0 ? oa : (seg == 1 ? ob : (seg == 2 ? oc : od));
      cvt8(src, dst, off);
    }
  }
}

// ---------------- mask compaction scan (one block, wave per batch) --------
__global__ void scan_k(const int* __restrict__ mask, int* __restrict__ idx,
                       u16* __restrict__ biasc, int* __restrict__ meta) {
  __shared__ int nv_sh[4];
  const int tid = (int)threadIdx.x;
  const int w = tid >> 6, lane = tid & 63;
  const int* mb = mask + w * SEQ;
  int cnt = 0;
  for (int it = 0; it < SEQ / 64; ++it) {
    const int i = it * 64 + lane;
    const bool m = mb[i] != 0;
    const unsigned long long bal = __ballot(m);
    const int pos = cnt + __popcll(bal & ((1ull << lane) - 1ull));
    if (m) idx[w * SEQ + pos] = i;
    cnt += __popcll(bal);
  }
  if (lane == 0) nv_sh[w] = cnt;
  __syncthreads();
  const int nv = nv_sh[w];
  const int npad = (nv + 255) & ~255;
  for (int j = nv + lane; j < npad; j += 64) idx[w * SEQ + j] = 0;
  for (int j = lane; j < SEQ; j += 64)
    biasc[w * SEQ + j] = (j < nv) ? f2bf(BIAS_VALID) : f2bf(BIAS_MASKED);
  if (tid == 0) {
    int off = 0;
    for (int b2 = 0; b2 < 4; ++b2) {
      const int nvb = nv_sh[b2];
      meta[b2] = off;
      meta[4 + b2] = (nvb + 63) >> 6;
      off += (nvb + 255) & ~255;
    }
    meta[8] = off;
  }
}

// ------- gather+convert key/value input rows into compacted matrices ------
__global__ void gathercvt_k(const float* __restrict__ keyf,
                            const float* __restrict__ valf,
                            const int* __restrict__ idx, const int* __restrict__ meta,
                            u16* __restrict__ xkc, u16* __restrict__ xvc) {
  const int b = (int)blockIdx.y;
  const int j = (int)blockIdx.x;
  const int mstart = meta[b];
  const int mend = (b < 3) ? meta[b + 1] : meta[8];
  if (mstart + j >= mend) return;
  const int src = idx[b * SEQ + j];
  const float* ks = keyf + ((size_t)b * SEQ + src) * DMODEL;
  const float* vs = valf + ((size_t)b * SEQ + src) * DMODEL;
  u16* kd = xkc + (size_t)(mstart + j) * DMODEL;
  u16* vd = xvc + (size_t)(mstart + j) * DMODEL;
  cvt8(ks, kd, (int)threadIdx.x);
  cvt8(vs, vd, (int)threadIdx.x);
}

// ======== 256x256 GEMM body (4-phase schedule; explicit bm/bn) ====
// outmode 0: bf16 C[m][n]; 1: f32 C[m][n]; 2: bf16 C^T[n][m] (stride 8192,
//            LDS-transpose epilogue for coalesced stores)
static __device__ void gemm_body(const u16* __restrict__ A, const u16* __restrict__ Bw,
                                 void* __restrict__ Cv, const int outmode,
                                 const int bm, const int bn, const int mlimit) {
  constexpr int M = 8192, N = 2048, K = 2048;
  constexpr int NT = K / 64;
  __shared__ u16 Ab[2][256 * 64];
  __shared__ u16 Bb[2][256 * 64];

  if (bm * 256 >= mlimit) return;

  const int tid = (int)threadIdx.x;
  const int wv = tid >> 6, lane = tid & 63;
  const int l32 = lane & 31, hi = lane >> 5;
  const int wm = wv >> 2, wn = wv & 3;

  const size_t arow0 = (size_t)bm * 256;
  const size_t brow0 = (size_t)bn * 256;

  const int srow = tid >> 3;
  const int scolb = (tid & 7) * 16;
  const int scol = (scolb ^ ((srow & 7) << 4)) >> 1;
  const u16* agp = A  + (arow0 + srow) * (size_t)K + scol;
  const u16* bgp = Bw + (brow0 + srow) * (size_t)K + scol;

  f32x16 acc[4][2];
#pragma unroll
  for (int mi = 0; mi < 4; ++mi)
#pragma unroll
    for (int ni = 0; ni < 2; ++ni)
#pragma unroll
      for (int r = 0; r < 16; ++r) acc[mi][ni][r] = 0.f;

  auto SH_A = [&](int kt2, u16* bufA, int half) {
#pragma unroll
    for (int j = 0; j < 2; ++j) {
      const int rb = half * 128 + j * 64;
      gload16(agp + (size_t)rb * K + kt2, bufA + (rb + wv * 8) * 64);
    }
  };
  auto SH_B = [&](int kt2, u16* bufB, int half) {
#pragma unroll
    for (int j = 0; j < 2; ++j) {
      const int rb = half * 128 + j * 64;
      gload16(bgp + (size_t)rb * K + kt2, bufB + (rb + wv * 8) * 64);
    }
  };
  auto LDA = [&](const u16* buf, int qm, s16x8* af) {
#pragma unroll
    for (int mb = 0; mb < 2; ++mb) {
      const int row = wm * 128 + qm * 64 + mb * 32 + l32;
#pragma unroll
      for (int ks = 0; ks < 4; ++ks) {
        const int cb = ((ks * 32 + hi * 16) ^ ((row & 7) << 4)) >> 1;
        af[mb * 4 + ks] = *(const s16x8*)&buf[row * 64 + cb];
      }
    }
  };
  auto LDB = [&](const u16* buf, int qn, s16x8* bfr) {
    const int row = wn * 64 + qn * 32 + l32;
#pragma unroll
    for (int ks = 0; ks < 4; ++ks) {
      const int cb = ((ks * 32 + hi * 16) ^ ((row & 7) << 4)) >> 1;
      bfr[ks] = *(const s16x8*)&buf[row * 64 + cb];
    }
  };
  auto MM = [&](const s16x8* af, const s16x8* bfr, int qm, int qn) {
    __builtin_amdgcn_s_setprio(1);
#pragma unroll
    for (int mb = 0; mb < 2; ++mb)
#pragma unroll
      for (int ks = 0; ks < 4; ++ks)
        acc[qm * 2 + mb][qn] = mfma32(af[mb * 4 + ks], bfr[ks], acc[qm * 2 + mb][qn]);
    __builtin_amdgcn_s_setprio(0);
  };

  // prologue: A(0),B(0) + B(1); vmcnt(4) completes tile-0's halves
  SH_A(0, Ab[0], 0); SH_A(0, Ab[0], 1);
  SH_B(0, Bb[0], 0); SH_B(0, Bb[0], 1);
  SH_B(64, Bb[1], 0); SH_B(64, Bb[1], 1);
  VMCNT4; BARRIER;

  for (int t = 0; t < NT; ++t) {
    u16* Ac = Ab[t & 1];
    u16* Bc = Bb[t & 1];
    u16* An = Ab[(t + 1) & 1];
    u16* Bn = Bb[t & 1];             // B(t+2) has same parity as t
    const int kA = (t + 1) * 64;
    const int kB = (t + 2) * 64;
    const bool stA = (t + 1 < NT);
    const bool stB = (t + 2 < NT);
    s16x8 af0[8], af1[8], bf0[4], bf1[4];

    // p1: quadrant (0,0); stage A-half0(t+1)
    LDA(Ac, 0, af0); LDB(Bc, 0, bf0);
    if (stA) SH_A(kA, An, 0);
    BARRIER; LGKM0;
    MM(af0, bf0, 0, 0);
    BARRIER;
    // p2: quadrant (0,1); stage A-half1(t+1)
    LDB(Bc, 1, bf1);
    if (stA) SH_A(kA, An, 1);
    BARRIER; LGKM0;
    MM(af0, bf1, 0, 1);
    BARRIER;
    // p3: quadrant (1,1); stage B-half0(t+2)
    LDA(Ac, 1, af1);
    if (stB) SH_B(kB, Bn, 0);
    BARRIER; LGKM0;
    MM(af1, bf1, 1, 1);
    BARRIER;
    // p4: quadrant (1,0); stage B-half1(t+2); counted vmcnt
    if (stB) { SH_B(kB, Bn, 1); VMCNT4; }
    else if (stA) { VMCNT0; }
    BARRIER; LGKM0;
    MM(af1, bf0, 1, 0);
    BARRIER;
  }

  const size_t row0 = arow0 + (size_t)wm * 128;
  const size_t col0 = brow0 + (size_t)wn * 64;
  if (outmode == 0) {
    u16* C = (u16*)Cv;
#pragma unroll
    for (int mi = 0; mi < 4; ++mi)
#pragma unroll
      for (int ni = 0; ni < 2; ++ni) {
        const size_t rbase = row0 + mi * 32 + 4 * hi;
        const size_t c = col0 + ni * 32 + l32;
#pragma unroll
        for (int q = 0; q < 4; ++q)
#pragma unroll
          for (int rr = 0; rr < 4; ++rr)
            C[(rbase + 8 * q + rr) * N + c] = f2bf(acc[mi][ni][q * 4 + rr]);
      }
  } else if (outmode == 1) {
    float* C = (float*)Cv;
#pragma unroll
    for (int mi = 0; mi < 4; ++mi)
#pragma unroll
      for (int ni = 0; ni < 2; ++ni) {
        const size_t rbase = row0 + mi * 32 + 4 * hi;
        const size_t c = col0 + ni * 32 + l32;
#pragma unroll
        for (int q = 0; q < 4; ++q)
#pragma unroll
          for (int rr = 0; rr < 4; ++rr)
            C[(rbase + 8 * q + rr) * N + c] = acc[mi][ni][q * 4 + rr];
      }
  } else {
    // C^T[n][m]: transpose 64-col chunks through LDS, then coalesced stores
    u16* T = &Ab[0][0];              // 64 x 264 u16 (staging dead)
    constexpr int RS = 264;
    u16* C = (u16*)Cv;
    for (int c = 0; c < 4; ++c) {
      BARRIER;
      if (wn == c) {
#pragma unroll
        for (int mi = 0; mi < 4; ++mi)
#pragma unroll
          for (int ni = 0; ni < 2; ++ni) {
            const int tok0 = wm * 128 + mi * 32 + 4 * hi;
            const int dc = ni * 32 + l32;
#pragma unroll
            for (int q = 0; q < 4; ++q) {
              s16x4 v;
#pragma unroll
              for (int rr = 0; rr < 4; ++rr) v[rr] = (short)f2bf(acc[mi][ni][q * 4 + rr]);
              *(s16x4*)&T[dc * RS + tok0 + 8 * q] = v;
            }
          }
      }
      BARRIER;
      const int dr = tid >> 3, tc = tid & 7;
      u16* dst = C + (brow0 + c * 64 + dr) * (size_t)M + arow0 + tc * 32;
      const u16* srcT = &T[dr * RS + tc * 32];
#pragma unroll
      for (int v4 = 0; v4 < 4; ++v4)
        *(s16x8*)(dst + v4 * 8) = *(const s16x8*)(srcT + v4 * 8);
    }
    BARRIER;   // T reuse safety if another gemm_body call follows
  }
}

// dynamic job-stealing fused q/k/v projections (256 blocks):
// job list: [0,256) q tiles (uniform first round), then [256,256+nact) k,
// then [.., +nact) v. Blocks grab jobs via device-scope atomic counter ->
// phases stay temporally adjacent (2-way mixing max, proven cheap).
__global__ __launch_bounds__(512, 2) void gemmqkv_k(
    const u16* __restrict__ xq, const u16* __restrict__ wq, u16* __restrict__ qout,
    const u16* __restrict__ xkc, const u16* __restrict__ wk, u16* __restrict__ kout,
    const u16* __restrict__ xvc, const u16* __restrict__ wv, u16* __restrict__ vtout,
    const int* __restrict__ meta, u32* __restrict__ ctr) {
  __shared__ int job_sh;
  const int Mc = meta[8];              // 256-aligned by scan_k
  const int nact = (Mc >> 8) * 8;      // active tiles per kv matrix
  const int njobs = 256 + 2 * nact;
  for (;;) {
    if (threadIdx.x == 0) job_sh = (int)atomicAdd(ctr, 1u);
    __syncthreads();
    const int j = job_sh;
    __syncthreads();                   // all read j before next overwrite
    if (j >= njobs) return;
    if (j < 256) {
      const int bn = (j >> 3) & 7;
      const int bm = (j & 7) * 4 + (j >> 6);
      gemm_body(xq, wq, (void*)qout, 0, bm, bn, 8192);
    } else if (j < 256 + nact) {
      const int g = j - 256;
      gemm_body(xkc, wk, (void*)kout, 0, g >> 3, g & 7, Mc);
    } else {
      const int g = j - 256 - nact;
      gemm_body(xvc, wv, (void*)vtout, 2, g >> 3, g & 7, Mc);
    }
  }
}

__global__ __launch_bounds__(512, 2) void gemmwo_k(const u16* __restrict__ A,
                                                   const u16* __restrict__ Bw,
                                                   float* __restrict__ C) {
  const int bid = (int)blockIdx.x;
  const int bn = (bid >> 3) & 7;
  const int bm = (bid & 7) * 4 + (bid >> 6);
  gemm_body(A, Bw, (void*)C, 1, bm, bn, 8192);
}

// -------- RoPE on q (first 512 dims) + global scale by QK_SCALE_LOG2 --------
__global__ void rope_k(u16* __restrict__ qb, const int* __restrict__ pos_ids) {
  const int row = (int)blockIdx.x;          // b*SEQ + s
  const int s = row & (SEQ - 1);
  const int t = (int)threadIdx.x;           // 0..255
  const float pos = (float)pos_ids[s];
  const float ang = pos * exp2f((float)t * (-13.287712379549449f / 256.0f));
  float sn, cs;
  sincosf(ang, &sn, &cs);
  u16* p = qb + (size_t)row * DMODEL;
  const float x = bf2f(p[t]);
  const float y = bf2f(p[t + 256]);
  p[t]       = f2bf((x * cs - y * sn) * QK_SCALE_LOG2);
  p[t + 256] = f2bf((y * cs + x * sn) * QK_SCALE_LOG2);
#pragma unroll
  for (int j = 0; j < 6; ++j) {
    const int d = 512 + t + 256 * j;
    p[d] = f2bf(bf2f(p[d]) * QK_SCALE_LOG2);
  }
}

// ---------------- flash attention over COMPACTED keys ----------------
__device__ __forceinline__ void attn_stage(u16* Ks, u16* Vs,
                                           const u16* kbase, const u16* vbase,
                                           int kt, int w, int lane) {
#pragma unroll
  for (int i = 0; i < 4; ++i) {   // K tile [64][128], 256B rows, XOR-swizzled
    const int row = w * 16 + i * 4 + (lane >> 4);
    const int srcb = ((lane & 15) * 16) ^ ((row & 7) << 4);
    gload16(kbase + (size_t)(kt + row) * DMODEL + (srcb >> 1), &Ks[(w * 16 + i * 4) * 128]);
  }
#pragma unroll
  for (int i = 0; i < 4; ++i) {   // V^T tile [128][64], 128B rows, XOR-swizzled
    const int row = w * 32 + i * 8 + (lane >> 3);
    const int srcb = ((lane & 7) * 16) ^ ((row & 7) << 4);
    gload16(vbase + (size_t)row * NB + kt + (srcb >> 1), &Vs[(w * 32 + i * 8) * 64]);
  }
}

__global__ __launch_bounds__(256) void attn_k(const u16* __restrict__ q,
                                              const u16* __restrict__ kc,
                                              const u16* __restrict__ vtc,
                                              const u16* __restrict__ biasc,
                                              const int* __restrict__ meta,
                                              u16* __restrict__ att) {
  __shared__ u16 Ks[2][64 * 128];
  __shared__ u16 Vs[2][128 * 64];

  const int tid = (int)threadIdx.x;
  const int w = tid >> 6, lane = tid & 63;
  const int l32 = lane & 31, hi = lane >> 5;

  const int bid = (int)blockIdx.x;
  const int sb = (bid & 7) * 128 + (bid >> 3);   // XCD swizzle (1024 wgs)
  const int qt = sb & 15;
  const int bg = sb >> 4;
  const int b = bg >> 4, g = bg & 15;

  const int mstart = meta[b];
  const int nt = meta[4 + b];      // ceil(nvalid/64) tiles

  const int qrow = qt * 128 + w * 32 + l32;
  const u16* qp = q + ((size_t)b * SEQ + qrow) * DMODEL + g * DH;
  s16x8 aq[8];
#pragma unroll
  for (int s = 0; s < 8; ++s) aq[s] = *(const s16x8*)(qp + s * 16 + hi * 8);

  const u32 one0 = (hi == 0) ? 0x00003F80u : 0u;
  const s16x8 bones = frag_from_words(one0, 0, 0, 0);
  const s16x8 allones = frag_from_words(0x3F803F80u, 0x3F803F80u, 0x3F803F80u, 0x3F803F80u);

  f32x16 oacc[4], lacc;
#pragma unroll
  for (int r = 0; r < 16; ++r) {
    lacc[r] = 0.f;
#pragma unroll
    for (int d0 = 0; d0 < 4; ++d0) oacc[d0][r] = 0.f;
  }

  const u16* kbase = kc + (size_t)mstart * DMODEL + g * DH;
  const u16* vbase = vtc + (size_t)(g * DH) * NB + mstart;
  const u16* bbase = biasc + b * SEQ;

  attn_stage(Ks[0], Vs[0], kbase, vbase, 0, w, lane);
  u16 bb0 = bbase[l32], bb1 = bbase[32 + l32];

  for (int t = 0; t < nt; ++t) {
    const int cur = t & 1;
    __syncthreads();   // tile t ready (its loads had a full tile to land)
    u16 bbn0 = bb0, bbn1 = bb1;
    if (t < nt - 1) {
      attn_stage(Ks[cur ^ 1], Vs[cur ^ 1], kbase, vbase, (t + 1) * 64, w, lane);
      bbn0 = bbase[(t + 1) * 64 + l32];
      bbn1 = bbase[(t + 1) * 64 + 32 + l32];
    }
    const u16* KsC = Ks[cur];
    const u16* VsC = Vs[cur];

    const s16x8 ab0 = frag_from_words((hi == 0) ? (u32)bb0 : 0u, 0, 0, 0);
    const s16x8 ab1 = frag_from_words((hi == 0) ? (u32)bb1 : 0u, 0, 0, 0);
    __builtin_amdgcn_s_setprio(1);
    f32x16 sacc0 = mfma32(ab0, bones, (f32x16)(0.f));
    f32x16 sacc1 = mfma32(ab1, bones, (f32x16)(0.f));

#pragma unroll
    for (int s = 0; s < 8; ++s) {
      const int byteoff = ((s * 32 + hi * 16) ^ ((l32 & 7) << 4)) >> 1;
      const s16x8 a0 = *(const s16x8*)&KsC[l32 * 128 + byteoff];
      const s16x8 a1 = *(const s16x8*)&KsC[(32 + l32) * 128 + byteoff];
      sacc0 = mfma32(a0, aq[s], sacc0);
      sacc1 = mfma32(a1, aq[s], sacc1);
    }
    __builtin_amdgcn_s_setprio(0);

    u32 pk0[8], pk1[8];
#pragma unroll
    for (int i = 0; i < 8; ++i) {
      pk0[i] = pack_bf16(EXP2(sacc0[2 * i]), EXP2(sacc0[2 * i + 1]));
      pk1[i] = pack_bf16(EXP2(sacc1[2 * i]), EXP2(sacc1[2 * i + 1]));
    }
    s16x8 pa[4];
#pragma unroll
    for (int grp = 0; grp < 4; ++grp) {
      u32* pk = (grp < 2) ? pk0 : pk1;
      const int o = (grp & 1) * 4;
      plswap(pk[o + 0], pk[o + 2]);
      plswap(pk[o + 1], pk[o + 3]);
      pa[grp] = frag_from_words(pk[o + 0], pk[o + 1], pk[o + 2], pk[o + 3]);
    }

    __builtin_amdgcn_s_setprio(1);
#pragma unroll
    for (int ks = 0; ks < 4; ++ks) lacc = mfma32(pa[ks], allones, lacc);

#pragma unroll
    for (int d0 = 0; d0 < 4; ++d0) {
      const int rowd = d0 * 32 + l32;
#pragma unroll
      for (int ks = 0; ks < 4; ++ks) {
        const int byteoff = ((ks * 32 + hi * 16) ^ ((rowd & 7) << 4)) >> 1;
        const s16x8 bv = *(const s16x8*)&VsC[rowd * 64 + byteoff];
        oacc[d0] = mfma32(pa[ks], bv, oacc[d0]);
      }
    }
    __builtin_amdgcn_s_setprio(0);
    bb0 = bbn0; bb1 = bbn1;
  }

  float rinv[16];
#pragma unroll
  for (int r = 0; r < 16; ++r) rinv[r] = 1.0f / lacc[r];
  u16* ob = att + ((size_t)b * SEQ + qt * 128 + w * 32) * DMODEL + g * DH;
#pragma unroll
  for (int d0 = 0; d0 < 4; ++d0)
#pragma unroll
    for (int r = 0; r < 16; ++r) {
      const int qloc = (r & 3) + 8 * (r >> 2) + 4 * hi;
      ob[(size_t)qloc * DMODEL + d0 * 32 + l32] = f2bf(oacc[d0][r] * rinv[r]);
    }
}

// ---------------- launch ----------------
extern "C" void kernel_launch(void* const* d_in, const int* in_sizes, int n_in,
                              void* d_out, int out_size, void* d_ws, size_t ws_size,
                              hipStream_t stream) {
  const float* query = (const float*)d_in[0];
  const float* key   = (const float*)d_in[1];
  const float* value = (const float*)d_in[2];
  const int*   maskp = (const int*)d_in[3];
  const int*   posp  = (const int*)d_in[4];
  const float* Wq    = (const float*)d_in[5];
  const float* Wk    = (const float*)d_in[6];
  const float* Wv    = (const float*)d_in[7];
  const float* Wo    = (const float*)d_in[8];

  char* ws = (char*)d_ws;
  const size_t MB = 1024ull * 1024ull;
  u16* wq_b = (u16*)(ws + 0 * MB);
  u16* wk_b = (u16*)(ws + 8 * MB);
  u16* wv_b = (u16*)(ws + 16 * MB);
  u16* wo_b = (u16*)(ws + 24 * MB);
  u16* xq   = (u16*)(ws + 32 * MB);    // query bf16; att reuses
  u16* xkc  = (u16*)(ws + 64 * MB);    // compacted key input bf16
  u16* xvc  = (u16*)(ws + 96 * MB);    // compacted value input bf16
  u16* qb   = (u16*)(ws + 128 * MB);
  u16* kc   = (u16*)(ws + 160 * MB);   // compacted K (post-proj)
  u16* vtc  = (u16*)(ws + 192 * MB);   // compacted V^T (post-proj), stride 8192
  char* aux = ws + 224 * MB;
  int* meta  = (int*)aux;                       // 64 B
  int* idx   = (int*)(aux + 256);               // 32 KiB
  u16* biasc = (u16*)(aux + 256 + 32768);       // 16 KiB
  u32* ctr   = (u32*)(aux + 256 + 32768 + 16384);
  u16* att   = xq;

  hipMemsetAsync(ctr, 0, 4, stream);
  scan_k<<<dim3(1), dim3(256), 0, stream>>>(maskp, idx, biasc, meta);
  cvtall_k<<<dim3(3072), dim3(256), 0, stream>>>(query, Wq, Wk, Wv, Wo,
                                                 xq, wq_b, wk_b, wv_b, wo_b);
  gathercvt_k<<<dim3(SEQ, NBATCH), dim3(256), 0, stream>>>(key, value, idx, meta, xkc, xvc);

  gemmqkv_k<<<dim3(256), dim3(512), 0, stream>>>(xq, wq_b, qb, xkc, wk_b, kc,
                                                 xvc, wv_b, vtc, meta, ctr);

  rope_k<<<dim3(NBATCH * SEQ), dim3(256), 0, stream>>>(qb, posp);

  attn_k<<<dim3(1024), dim3(256), 0, stream>>>(qb, kc, vtc, biasc, meta, att);

  gemmwo_k<<<dim3(256), dim3(512), 0, stream>>>(att, wo_b, (float*)d_out);

  (void)in_sizes; (void)n_in; (void)out_size; (void)ws_size;
}

// Round 19
// 503.762 us; speedup vs baseline: 1.0400x; 1.0400x over previous
//
#include <hip/hip_runtime.h>
#include <hip/hip_bf16.h>
#include <type_traits>
#include <utility>

typedef unsigned short u16;
typedef unsigned int u32;
typedef __attribute__((ext_vector_type(8))) short  s16x8;
typedef __attribute__((ext_vector_type(4))) short  s16x4;
typedef __attribute__((ext_vector_type(4))) float  f32x4;
typedef __attribute__((ext_vector_type(16))) float f32x16;
typedef __bf16 bf16x8_t __attribute__((ext_vector_type(8)));
typedef __bf16 bf16x2_t __attribute__((ext_vector_type(2)));

#define SEQ 2048
#define DMODEL 2048
#define NBATCH 4
#define DH 128
#define NB (NBATCH * SEQ)

// Q pre-scale: (1/sqrt(128)) * log2(e)  -> scores come out in log2 domain
#define QK_SCALE_LOG2 0.12754375f
// bias constants (log2 domain): valid = -24*log2e ; masked/pad = huge negative
#define BIAS_VALID  (-34.624681f)
#define BIAS_MASKED (-180.0f)

#if __has_builtin(__builtin_amdgcn_exp2f)
#define EXP2(x) __builtin_amdgcn_exp2f(x)
#else
#define EXP2(x) exp2f(x)
#endif

#define BARRIER __builtin_amdgcn_s_barrier()
#define LGKM0  asm volatile("s_waitcnt lgkmcnt(0)" ::: "memory")
#define VMCNT4 asm volatile("s_waitcnt vmcnt(4)" ::: "memory")
#define VMCNT0 asm volatile("s_waitcnt vmcnt(0)" ::: "memory")

static __device__ __forceinline__ u16 f2bf(float f) {
  unsigned u = __float_as_uint(f);
  u += 0x7fffu + ((u >> 16) & 1u);
  return (u16)(u >> 16);
}
static __device__ __forceinline__ float bf2f(u16 h) {
  return __uint_as_float(((unsigned)h) << 16);
}
static __device__ __forceinline__ u32 pack_bf16(float a, float b) {
  bf16x2_t t; t[0] = (__bf16)a; t[1] = (__bf16)b;
  return __builtin_bit_cast(u32, t);
}
// v_permlane32_swap_b32: after the op, a = {a.row0, b.row0}, b = {a.row1, b.row1}
static __device__ __forceinline__ void plswap(u32& a, u32& b) {
  asm("v_permlane32_swap_b32 %0, %1" : "+v"(a), "+v"(b));
}

// ---- MFMA wrappers: robust to short8 vs bf16x8 builtin signature ----
template <typename T, typename = void>
struct mfma_takes : std::false_type {};
template <typename T>
struct mfma_takes<T, std::void_t<decltype(__builtin_amdgcn_mfma_f32_16x16x32_bf16(
    std::declval<T>(), std::declval<T>(), std::declval<f32x4>(), 0, 0, 0))>>
    : std::true_type {};
using mfma_frag_t = std::conditional_t<mfma_takes<s16x8>::value, s16x8, bf16x8_t>;

static __device__ __forceinline__ f32x16 mfma32(s16x8 a, s16x8 b, f32x16 c) {
  return __builtin_amdgcn_mfma_f32_32x32x16_bf16(
      __builtin_bit_cast(mfma_frag_t, a), __builtin_bit_cast(mfma_frag_t, b), c, 0, 0, 0);
}

typedef const void __attribute__((address_space(1)))* gas_ptr;
typedef void __attribute__((address_space(3)))* las_ptr;
static __device__ __forceinline__ void gload16(const void* g, void* l) {
  __builtin_amdgcn_global_load_lds((gas_ptr)g, (las_ptr)l, 16, 0, 0);
}

static __device__ __forceinline__ s16x8 frag_from_words(u32 w0, u32 w1, u32 w2, u32 w3) {
  union { u32 w[4]; s16x8 v; } u;
  u.w[0] = w0; u.w[1] = w1; u.w[2] = w2; u.w[3] = w3;
  return u.v;
}

// ---------------- f32 -> bf16 convert helpers ----------------
static __device__ __forceinline__ void cvt8(const float* src, u16* dst, int i) {
  const float4* p = (const float4*)src + (size_t)i * 2;
  float4 a = p[0], b4 = p[1];
  s16x8 o;
  o[0] = (short)f2bf(a.x);  o[1] = (short)f2bf(a.y);
  o[2] = (short)f2bf(a.z);  o[3] = (short)f2bf(a.w);
  o[4] = (short)f2bf(b4.x); o[5] = (short)f2bf(b4.y);
  o[6] = (short)f2bf(b4.z); o[7] = (short)f2bf(b4.w);
  *(s16x8*)(dst + (size_t)i * 8) = o;
}

// query + 4 weights in one launch
__global__ void cvtall_k(const float* __restrict__ q, const float* __restrict__ a,
                         const float* __restrict__ b, const float* __restrict__ c,
                         const float* __restrict__ d, u16* __restrict__ oq,
                         u16* __restrict__ oa, u16* __restrict__ ob,
                         u16* __restrict__ oc, u16* __restrict__ od) {
  const int nq = 1 << 21, nw = 1 << 19;
  const int total = nq + 4 * nw;
  const int stride = (int)(gridDim.x * blockDim.x);
  for (int i = (int)(blockIdx.x * blockDim.x + threadIdx.x); i < total; i += stride) {
    if (i < nq) {
      cvt8(q, oq, i);
    } else {
      const int j = i - nq;
      const int seg = j >> 19, off = j & (nw - 1);
      const float* src = seg == 0 ? a : (seg == 1 ? b : (seg == 2 ? c : d));
      u16* dst = seg == 0 ? oa : (seg == 1 ? ob : (seg == 2 ? oc : od));
      cvt8(src, dst, off);
    }
  }
}

// ---------------- mask compaction scan (one block, wave per batch) --------
__global__ void scan_k(const int* __restrict__ mask, int* __restrict__ idx,
                       u16* __restrict__ biasc, int* __restrict__ meta) {
  __shared__ int nv_sh[4];
  const int tid = (int)threadIdx.x;
  const int w = tid >> 6, lane = tid & 63;
  const int* mb = mask + w * SEQ;
  int cnt = 0;
  for (int it = 0; it < SEQ / 64; ++it) {
    const int i = it * 64 + lane;
    const bool m = mb[i] != 0;
    const unsigned long long bal = __ballot(m);
    const int pos = cnt + __popcll(bal & ((1ull << lane) - 1ull));
    if (m) idx[w * SEQ + pos] = i;
    cnt += __popcll(bal);
  }
  if (lane == 0) nv_sh[w] = cnt;
  __syncthreads();
  const int nv = nv_sh[w];
  const int npad = (nv + 255) & ~255;
  for (int j = nv + lane; j < npad; j += 64) idx[w * SEQ + j] = 0;
  for (int j = lane; j < SEQ; j += 64)
    biasc[w * SEQ + j] = (j < nv) ? f2bf(BIAS_VALID) : f2bf(BIAS_MASKED);
  if (tid == 0) {
    int off = 0;
    for (int b2 = 0; b2 < 4; ++b2) {
      const int nvb = nv_sh[b2];
      meta[b2] = off;
      meta[4 + b2] = (nvb + 63) >> 6;
      off += (nvb + 255) & ~255;
    }
    meta[8] = off;
  }
}

// ------- gather+convert key/value input rows into compacted matrices ------
__global__ void gathercvt_k(const float* __restrict__ keyf,
                            const float* __restrict__ valf,
                            const int* __restrict__ idx, const int* __restrict__ meta,
                            u16* __restrict__ xkc, u16* __restrict__ xvc) {
  const int b = (int)blockIdx.y;
  const int j = (int)blockIdx.x;
  const int mstart = meta[b];
  const int mend = (b < 3) ? meta[b + 1] : meta[8];
  if (mstart + j >= mend) return;
  const int src = idx[b * SEQ + j];
  const float* ks = keyf + ((size_t)b * SEQ + src) * DMODEL;
  const float* vs = valf + ((size_t)b * SEQ + src) * DMODEL;
  u16* kd = xkc + (size_t)(mstart + j) * DMODEL;
  u16* vd = xvc + (size_t)(mstart + j) * DMODEL;
  cvt8(ks, kd, (int)threadIdx.x);
  cvt8(vs, vd, (int)threadIdx.x);
}

// ======== 256x256 GEMM body (4-phase schedule; explicit bm/bn) ====
// outmode 0: bf16 C[m][n]; 1: f32 C[m][n]; 2: bf16 C^T[n][m] (stride 8192,
//            LDS-transpose epilogue for coalesced stores)
static __device__ void gemm_body(const u16* __restrict__ A, const u16* __restrict__ Bw,
                                 void* __restrict__ Cv, const int outmode,
                                 const int bm, const int bn, const int mlimit) {
  constexpr int M = 8192, N = 2048, K = 2048;
  constexpr int NT = K / 64;
  __shared__ u16 Ab[2][256 * 64];
  __shared__ u16 Bb[2][256 * 64];

  if (bm * 256 >= mlimit) return;

  const int tid = (int)threadIdx.x;
  const int wv = tid >> 6, lane = tid & 63;
  const int l32 = lane & 31, hi = lane >> 5;
  const int wm = wv >> 2, wn = wv & 3;

  const size_t arow0 = (size_t)bm * 256;
  const size_t brow0 = (size_t)bn * 256;

  const int srow = tid >> 3;
  const int scolb = (tid & 7) * 16;
  const int scol = (scolb ^ ((srow & 7) << 4)) >> 1;
  const u16* agp = A  + (arow0 + srow) * (size_t)K + scol;
  const u16* bgp = Bw + (brow0 + srow) * (size_t)K + scol;

  f32x16 acc[4][2];
#pragma unroll
  for (int mi = 0; mi < 4; ++mi)
#pragma unroll
    for (int ni = 0; ni < 2; ++ni)
#pragma unroll
      for (int r = 0; r < 16; ++r) acc[mi][ni][r] = 0.f;

  auto SH_A = [&](int kt2, u16* bufA, int half) {
#pragma unroll
    for (int j = 0; j < 2; ++j) {
      const int rb = half * 128 + j * 64;
      gload16(agp + (size_t)rb * K + kt2, bufA + (rb + wv * 8) * 64);
    }
  };
  auto SH_B = [&](int kt2, u16* bufB, int half) {
#pragma unroll
    for (int j = 0; j < 2; ++j) {
      const int rb = half * 128 + j * 64;
      gload16(bgp + (size_t)rb * K + kt2, bufB + (rb + wv * 8) * 64);
    }
  };
  auto LDA = [&](const u16* buf, int qm, s16x8* af) {
#pragma unroll
    for (int mb = 0; mb < 2; ++mb) {
      const int row = wm * 128 + qm * 64 + mb * 32 + l32;
#pragma unroll
      for (int ks = 0; ks < 4; ++ks) {
        const int cb = ((ks * 32 + hi * 16) ^ ((row & 7) << 4)) >> 1;
        af[mb * 4 + ks] = *(const s16x8*)&buf[row * 64 + cb];
      }
    }
  };
  auto LDB = [&](const u16* buf, int qn, s16x8* bfr) {
    const int row = wn * 64 + qn * 32 + l32;
#pragma unroll
    for (int ks = 0; ks < 4; ++ks) {
      const int cb = ((ks * 32 + hi * 16) ^ ((row & 7) << 4)) >> 1;
      bfr[ks] = *(const s16x8*)&buf[row * 64 + cb];
    }
  };
  auto MM = [&](const s16x8* af, const s16x8* bfr, int qm, int qn) {
    __builtin_amdgcn_s_setprio(1);
#pragma unroll
    for (int mb = 0; mb < 2; ++mb)
#pragma unroll
      for (int ks = 0; ks < 4; ++ks)
        acc[qm * 2 + mb][qn] = mfma32(af[mb * 4 + ks], bfr[ks], acc[qm * 2 + mb][qn]);
    __builtin_amdgcn_s_setprio(0);
  };

  // prologue: A(0),B(0) + B(1); vmcnt(4) completes tile-0's halves
  SH_A(0, Ab[0], 0); SH_A(0, Ab[0], 1);
  SH_B(0, Bb[0], 0); SH_B(0, Bb[0], 1);
  SH_B(64, Bb[1], 0); SH_B(64, Bb[1], 1);
  VMCNT4; BARRIER;

  for (int t = 0; t < NT; ++t) {
    u16* Ac = Ab[t & 1];
    u16* Bc = Bb[t & 1];
    u16* An = Ab[(t + 1) & 1];
    u16* Bn = Bb[t & 1];             // B(t+2) has same parity as t
    const int kA = (t + 1) * 64;
    const int kB = (t + 2) * 64;
    const bool stA = (t + 1 < NT);
    const bool stB = (t + 2 < NT);
    s16x8 af0[8], af1[8], bf0[4], bf1[4];

    // p1: quadrant (0,0); stage A-half0(t+1)
    LDA(Ac, 0, af0); LDB(Bc, 0, bf0);
    if (stA) SH_A(kA, An, 0);
    BARRIER; LGKM0;
    MM(af0, bf0, 0, 0);
    BARRIER;
    // p2: quadrant (0,1); stage A-half1(t+1)
    LDB(Bc, 1, bf1);
    if (stA) SH_A(kA, An, 1);
    BARRIER; LGKM0;
    MM(af0, bf1, 0, 1);
    BARRIER;
    // p3: quadrant (1,1); stage B-half0(t+2)
    LDA(Ac, 1, af1);
    if (stB) SH_B(kB, Bn, 0);
    BARRIER; LGKM0;
    MM(af1, bf1, 1, 1);
    BARRIER;
    // p4: quadrant (1,0); stage B-half1(t+2); counted vmcnt
    if (stB) { SH_B(kB, Bn, 1); VMCNT4; }
    else if (stA) { VMCNT0; }
    BARRIER; LGKM0;
    MM(af1, bf0, 1, 0);
    BARRIER;
  }

  const size_t row0 = arow0 + (size_t)wm * 128;
  const size_t col0 = brow0 + (size_t)wn * 64;
  if (outmode == 0) {
    u16* C = (u16*)Cv;
#pragma unroll
    for (int mi = 0; mi < 4; ++mi)
#pragma unroll
      for (int ni = 0; ni < 2; ++ni) {
        const size_t rbase = row0 + mi * 32 + 4 * hi;
        const size_t c = col0 + ni * 32 + l32;
#pragma unroll
        for (int q = 0; q < 4; ++q)
#pragma unroll
          for (int rr = 0; rr < 4; ++rr)
            C[(rbase + 8 * q + rr) * N + c] = f2bf(acc[mi][ni][q * 4 + rr]);
      }
  } else if (outmode == 1) {
    float* C = (float*)Cv;
#pragma unroll
    for (int mi = 0; mi < 4; ++mi)
#pragma unroll
      for (int ni = 0; ni < 2; ++ni) {
        const size_t rbase = row0 + mi * 32 + 4 * hi;
        const size_t c = col0 + ni * 32 + l32;
#pragma unroll
        for (int q = 0; q < 4; ++q)
#pragma unroll
          for (int rr = 0; rr < 4; ++rr)
            C[(rbase + 8 * q + rr) * N + c] = acc[mi][ni][q * 4 + rr];
      }
  } else {
    // C^T[n][m]: transpose 64-col chunks through LDS, then coalesced stores
    u16* T = &Ab[0][0];              // 64 x 264 u16 (staging dead)
    constexpr int RS = 264;
    u16* C = (u16*)Cv;
    for (int c = 0; c < 4; ++c) {
      BARRIER;
      if (wn == c) {
#pragma unroll
        for (int mi = 0; mi < 4; ++mi)
#pragma unroll
          for (int ni = 0; ni < 2; ++ni) {
            const int tok0 = wm * 128 + mi * 32 + 4 * hi;
            const int dc = ni * 32 + l32;
#pragma unroll
            for (int q = 0; q < 4; ++q) {
              s16x4 v;
#pragma unroll
              for (int rr = 0; rr < 4; ++rr) v[rr] = (short)f2bf(acc[mi][ni][q * 4 + rr]);
              *(s16x4*)&T[dc * RS + tok0 + 8 * q] = v;
            }
          }
      }
      BARRIER;
      const int dr = tid >> 3, tc = tid & 7;
      u16* dst = C + (brow0 + c * 64 + dr) * (size_t)M + arow0 + tc * 32;
      const u16* srcT = &T[dr * RS + tc * 32];
#pragma unroll
      for (int v4 = 0; v4 < 4; ++v4)
        *(s16x8*)(dst + v4 * 8) = *(const s16x8*)(srcT + v4 * 8);
    }
    BARRIER;   // T reuse safety if another gemm_body call follows
  }
}

// q projection: uniform 256-block launch (one clean round)
__global__ __launch_bounds__(512, 2) void gemmq_k(const u16* __restrict__ xq,
                                                  const u16* __restrict__ wq,
                                                  u16* __restrict__ qout) {
  const int bid = (int)blockIdx.x;
  const int bn = (bid >> 3) & 7;
  const int bm = (bid & 7) * 4 + (bid >> 6);
  gemm_body(xq, wq, (void*)qout, 0, bm, bn, 8192);
}

// k+v projections: same (bm,bn) for both -> active blocks do exactly 2 tiles,
// inactive exit; machine-wide k-phase and v-phase stay time-aligned (uniform).
__global__ __launch_bounds__(512, 2) void gemmkv_k(
    const u16* __restrict__ xkc, const u16* __restrict__ wk, u16* __restrict__ kout,
    const u16* __restrict__ xvc, const u16* __restrict__ wv, u16* __restrict__ vtout,
    const int* __restrict__ meta) {
  const int bid = (int)blockIdx.x;
  const int bn = (bid >> 3) & 7;
  const int bm = (bid & 7) * 4 + (bid >> 6);
  const int mc = meta[8];
  gemm_body(xkc, wk, (void*)kout, 0, bm, bn, mc);
  gemm_body(xvc, wv, (void*)vtout, 2, bm, bn, mc);
}

__global__ __launch_bounds__(512, 2) void gemmwo_k(const u16* __restrict__ A,
                                                   const u16* __restrict__ Bw,
                                                   float* __restrict__ C) {
  const int bid = (int)blockIdx.x;
  const int bn = (bid >> 3) & 7;
  const int bm = (bid & 7) * 4 + (bid >> 6);
  gemm_body(A, Bw, (void*)C, 1, bm, bn, 8192);
}

// -------- RoPE on q (first 512 dims) + global scale by QK_SCALE_LOG2 --------
__global__ void rope_k(u16* __restrict__ qb, const int* __restrict__ pos_ids) {
  const int row = (int)blockIdx.x;          // b*SEQ + s
  const int s = row & (SEQ - 1);
  const int t = (int)threadIdx.x;           // 0..255
  const float pos = (float)pos_ids[s];
  const float ang = pos * exp2f((float)t * (-13.287712379549449f / 256.0f));
  float sn, cs;
  sincosf(ang, &sn, &cs);
  u16* p = qb + (size_t)row * DMODEL;
  const float x = bf2f(p[t]);
  const float y = bf2f(p[t + 256]);
  p[t]       = f2bf((x * cs - y * sn) * QK_SCALE_LOG2);
  p[t + 256] = f2bf((y * cs + x * sn) * QK_SCALE_LOG2);
#pragma unroll
  for (int j = 0; j < 6; ++j) {
    const int d = 512 + t + 256 * j;
    p[d] = f2bf(bf2f(p[d]) * QK_SCALE_LOG2);
  }
}

// ---------------- flash attention over COMPACTED keys ----------------
__device__ __forceinline__ void attn_stage(u16* Ks, u16* Vs,
                                           const u16* kbase, const u16* vbase,
                                           int kt, int w, int lane) {
#pragma unroll
  for (int i = 0; i < 4; ++i) {   // K tile [64][128], 256B rows, XOR-swizzled
    const int row = w * 16 + i * 4 + (lane >> 4);
    const int srcb = ((lane & 15) * 16) ^ ((row & 7) << 4);
    gload16(kbase + (size_t)(kt + row) * DMODEL + (srcb >> 1), &Ks[(w * 16 + i * 4) * 128]);
  }
#pragma unroll
  for (int i = 0; i < 4; ++i) {   // V^T tile [128][64], 128B rows, XOR-swizzled
    const int row = w * 32 + i * 8 + (lane >> 3);
    const int srcb = ((lane & 7) * 16) ^ ((row & 7) << 4);
    gload16(vbase + (size_t)row * NB + kt + (srcb >> 1), &Vs[(w * 32 + i * 8) * 64]);
  }
}

__global__ __launch_bounds__(256) void attn_k(const u16* __restrict__ q,
                                              const u16* __restrict__ kc,
                                              const u16* __restrict__ vtc,
                                              const u16* __restrict__ biasc,
                                              const int* __restrict__ meta,
                                              u16* __restrict__ att) {
  __shared__ u16 Ks[2][64 * 128];
  __shared__ u16 Vs[2][128 * 64];

  const int tid = (int)threadIdx.x;
  const int w = tid >> 6, lane = tid & 63;
  const int l32 = lane & 31, hi = lane >> 5;

  const int bid = (int)blockIdx.x;
  const int sb = (bid & 7) * 128 + (bid >> 3);   // XCD swizzle (1024 wgs)
  const int qt = sb & 15;
  const int bg = sb >> 4;
  const int b = bg >> 4, g = bg & 15;

  const int mstart = meta[b];
  const int nt = meta[4 + b];      // ceil(nvalid/64) tiles

  const int qrow = qt * 128 + w * 32 + l32;
  const u16* qp = q + ((size_t)b * SEQ + qrow) * DMODEL + g * DH;
  s16x8 aq[8];
#pragma unroll
  for (int s = 0; s < 8; ++s) aq[s] = *(const s16x8*)(qp + s * 16 + hi * 8);

  const u32 one0 = (hi == 0) ? 0x00003F80u : 0u;
  const s16x8 bones = frag_from_words(one0, 0, 0, 0);
  const s16x8 allones = frag_from_words(0x3F803F80u, 0x3F803F80u, 0x3F803F80u, 0x3F803F80u);

  f32x16 oacc[4], lacc;
#pragma unroll
  for (int r = 0; r < 16; ++r) {
    lacc[r] = 0.f;
#pragma unroll
    for (int d0 = 0; d0 < 4; ++d0) oacc[d0][r] = 0.f;
  }

  const u16* kbase = kc + (size_t)mstart * DMODEL + g * DH;
  const u16* vbase = vtc + (size_t)(g * DH) * NB + mstart;
  const u16* bbase = biasc + b * SEQ;

  attn_stage(Ks[0], Vs[0], kbase, vbase, 0, w, lane);
  u16 bb0 = bbase[l32], bb1 = bbase[32 + l32];

  for (int t = 0; t < nt; ++t) {
    const int cur = t & 1;
    __syncthreads();   // tile t ready (its loads had a full tile to land)
    u16 bbn0 = bb0, bbn1 = bb1;
    if (t < nt - 1) {
      attn_stage(Ks[cur ^ 1], Vs[cur ^ 1], kbase, vbase, (t + 1) * 64, w, lane);
      bbn0 = bbase[(t + 1) * 64 + l32];
      bbn1 = bbase[(t + 1) * 64 + 32 + l32];
    }
    const u16* KsC = Ks[cur];
    const u16* VsC = Vs[cur];

    const s16x8 ab0 = frag_from_words((hi == 0) ? (u32)bb0 : 0u, 0, 0, 0);
    const s16x8 ab1 = frag_from_words((hi == 0) ? (u32)bb1 : 0u, 0, 0, 0);
    __builtin_amdgcn_s_setprio(1);
    f32x16 sacc0 = mfma32(ab0, bones, (f32x16)(0.f));
    f32x16 sacc1 = mfma32(ab1, bones, (f32x16)(0.f));

#pragma unroll
    for (int s = 0; s < 8; ++s) {
      const int byteoff = ((s * 32 + hi * 16) ^ ((l32 & 7) << 4)) >> 1;
      const s16x8 a0 = *(const s16x8*)&KsC[l32 * 128 + byteoff];
      const s16x8 a1 = *(const s16x8*)&KsC[(32 + l32) * 128 + byteoff];
      sacc0 = mfma32(a0, aq[s], sacc0);
      sacc1 = mfma32(a1, aq[s], sacc1);
    }
    __builtin_amdgcn_s_setprio(0);

    u32 pk0[8], pk1[8];
#pragma unroll
    for (int i = 0; i < 8; ++i) {
      pk0[i] = pack_bf16(EXP2(sacc0[2 * i]), EXP2(sacc0[2 * i + 1]));
      pk1[i] = pack_bf16(EXP2(sacc1[2 * i]), EXP2(sacc1[2 * i + 1]));
    }
    s16x8 pa[4];
#pragma unroll
    for (int grp = 0; grp < 4; ++grp) {
      u32* pk = (grp < 2) ? pk0 : pk1;
      const int o = (grp & 1) * 4;
      plswap(pk[o + 0], pk[o + 2]);
      plswap(pk[o + 1], pk[o + 3]);
      pa[grp] = frag_from_words(pk[o + 0], pk[o + 1], pk[o + 2], pk[o + 3]);
    }

    __builtin_amdgcn_s_setprio(1);
#pragma unroll
    for (int ks = 0; ks < 4; ++ks) lacc = mfma32(pa[ks], allones, lacc);

#pragma unroll
    for (int d0 = 0; d0 < 4; ++d0) {
      const int rowd = d0 * 32 + l32;
#pragma unroll
      for (int ks = 0; ks < 4; ++ks) {
        const int byteoff = ((ks * 32 + hi * 16) ^ ((rowd & 7) << 4)) >> 1;
        const s16x8 bv = *(const s16x8*)&VsC[rowd * 64 + byteoff];
        oacc[d0] = mfma32(pa[ks], bv, oacc[d0]);
      }
    }
    __builtin_amdgcn_s_setprio(0);
    bb0 = bbn0; bb1 = bbn1;
  }

  float rinv[16];
#pragma unroll
  for (int r = 0; r < 16; ++r) rinv[r] = 1.0f / lacc[r];
  u16* ob = att + ((size_t)b * SEQ + qt * 128 + w * 32) * DMODEL + g * DH;
#pragma unroll
  for (int d0 = 0; d0 < 4; ++d0)
#pragma unroll
    for (int r = 0; r < 16; ++r) {
      const int qloc = (r & 3) + 8 * (r >> 2) + 4 * hi;
      ob[(size_t)qloc * DMODEL + d0 * 32 + l32] = f2bf(oacc[d0][r] * rinv[r]);
    }
}

// ---------------- launch ----------------
extern "C" void kernel_launch(void* const* d_in, const int* in_sizes, int n_in,
                              void* d_out, int out_size, void* d_ws, size_t ws_size,
                              hipStream_t stream) {
  const float* query = (const float*)d_in[0];
  const float* key   = (const float*)d_in[1];
  const float* value = (const float*)d_in[2];
  const int*   maskp = (const int*)d_in[3];
  const int*   posp  = (const int*)d_in[4];
  const float* Wq    = (const float*)d_in[5];
  const float* Wk    = (const float*)d_in[6];
  const float* Wv    = (const float*)d_in[7];
  const float* Wo    = (const float*)d_in[8];

  char* ws = (char*)d_ws;
  const size_t MB = 1024ull * 1024ull;
  u16* wq_b = (u16*)(ws + 0 * MB);
  u16* wk_b = (u16*)(ws + 8 * MB);
  u16* wv_b = (u16*)(ws + 16 * MB);
  u16* wo_b = (u16*)(ws + 24 * MB);
  u16* xq   = (u16*)(ws + 32 * MB);    // query bf16; att reuses
  u16* xkc  = (u16*)(ws + 64 * MB);    // compacted key input bf16
  u16* xvc  = (u16*)(ws + 96 * MB);    // compacted value input bf16
  u16* qb   = (u16*)(ws + 128 * MB);
  u16* kc   = (u16*)(ws + 160 * MB);   // compacted K (post-proj)
  u16* vtc  = (u16*)(ws + 192 * MB);   // compacted V^T (post-proj), stride 8192
  char* aux = ws + 224 * MB;
  int* meta  = (int*)aux;                       // 64 B
  int* idx   = (int*)(aux + 256);               // 32 KiB
  u16* biasc = (u16*)(aux + 256 + 32768);       // 16 KiB
  u16* att   = xq;

  scan_k<<<dim3(1), dim3(256), 0, stream>>>(maskp, idx, biasc, meta);
  cvtall_k<<<dim3(3072), dim3(256), 0, stream>>>(query, Wq, Wk, Wv, Wo,
                                                 xq, wq_b, wk_b, wv_b, wo_b);

  // q projection first (doesn't need the gather); k/v after gathercvt
  gemmq_k<<<dim3(256), dim3(512), 0, stream>>>(xq, wq_b, qb);

  gathercvt_k<<<dim3(SEQ, NBATCH), dim3(256), 0, stream>>>(key, value, idx, meta, xkc, xvc);

  gemmkv_k<<<dim3(256), dim3(512), 0, stream>>>(xkc, wk_b, kc, xvc, wv_b, vtc, meta);

  rope_k<<<dim3(NBATCH * SEQ), dim3(256), 0, stream>>>(qb, posp);

  attn_k<<<dim3(1024), dim3(256), 0, stream>>>(qb, kc, vtc, biasc, meta, att);

  gemmwo_k<<<dim3(256), dim3(512), 0, stream>>>(att, wo_b, (float*)d_out);

  (void)in_sizes; (void)n_in; (void)out_size; (void)ws_size;
}